// Round 2
// baseline (7998.014 us; speedup 1.0000x reference)
//
#include <hip/hip_runtime.h>

// LSTM forward, persistent-kernel, R8:
//   R6 post-mortem: 2276us = 4.45us/step; MfmaUtil 6%, VALUBusy 13%, HBM 1.5%
//   -> step time is inter-block H/flag latency (3-4 LLC roundtrips/step).
//   WRITE_SIZE 150MB = sc1 Hbuf/flag stores writing through LLC to HBM.
//   R7 (no result: infra exception) -> R8 hardened XCD-local fast path:
//   - grid 256 (1 block/CU). Consensus phase A: every block publishes
//     s_getreg(XCC_ID) [builtin imm, not asm-parser-dependent]; bounded poll;
//     CAS'd decision word 1 (balanced 32/XCD? -> FAST-try else SLOW).
//   - Consensus phase B (FAST-try only): bounded COHERENCE HANDSHAKE --
//     each block plain-stores a token and sc0-polls its 32 claimed-group
//     tokens; verified-counter + CAS'd decision word 2 commits FAST only if
//     all 256 blocks proved intra-group L2 visibility. Every loop bounded +
//     escapes via decision word -> deadlock-free; any failure -> SLOW (=R6
//     proven agent/LLC protocol, bid<128 mapping).
//   - FAST: H publish + flags = workgroup-scope plain stores (stay in XCD
//     L2); poll = explicit sc0 load asm (L1 bypass, L2 hit); H staging DMA
//     aux=1 (sc0). SLOW: aux=17 + agent-scope sc1 ops exactly as R6.
//   - both modes: per-wave flag poll (3rd barrier removed), x-prefetch after
//     store-drain barrier (overlaps flag+poll+DMA), 4B-stride flags.

#define NB    128
#define GRID  256
#define SEQ   512
#define BATCH 64
#define DIM   256
#define HU    1024
#define ROWU  1032   // u16 row stride: 2064 B -> b128 reads 2-way bank (free)

// flags layout (u32 indices; k_prep zeroes [0,4096))
#define F_STEP 0      // [0,128)   step flags: bb*32+bj
#define F_XMAP 512    // [512,768) xcc map per block
#define F_TOK  768    // [768,1024) handshake tokens: xcc*32+rank
#define F_DEC1 1024   // placement decision: 0=unset 1=SLOW 2=FAST-try
#define F_DEC2 1025   // final decision:     0=unset 1=SLOW 2=FAST
#define F_VER  1026   // handshake verified-block counter

#define HWREG_XCC_ID_IMM ((31 << 11) | 20)   // hwreg(HW_REG_XCC_ID,0,32)

typedef unsigned short u16;
typedef unsigned int   u32;
typedef unsigned long long u64;
typedef __attribute__((ext_vector_type(8))) short  short8;
typedef __attribute__((ext_vector_type(4))) float  f32x4;

typedef const __attribute__((address_space(1))) void* gptr_t;
typedef __attribute__((address_space(3))) void*       lptr_t;

__device__ __forceinline__ u16 f2bf(float x) {
  u32 u = __float_as_uint(x);
  u32 r = (u + 0x7FFFu + ((u >> 16) & 1u)) >> 16;   // RNE
  return (u16)r;
}
__device__ __forceinline__ float sigf(float x)  { return 1.0f / (1.0f + __expf(-x)); }
__device__ __forceinline__ float tanhfast(float x) { return 1.0f - 2.0f / (1.0f + __expf(2.0f * x)); }
__device__ __forceinline__ short8 cv8(uint4 v) {
  union { uint4 d; short8 s; } u; u.d = v; return u.s;
}
// L1-bypassing load that stops at the XCD L2 (sc0 only; sc1 would read LLC
// and could miss data sitting dirty in the local L2).
__device__ __forceinline__ u32 l2_load(const u32* p) {
  u64 a = (u64)p; u32 v;
  asm volatile("global_load_dword %0, %1, off sc0\n\ts_waitcnt vmcnt(0)"
               : "=v"(v) : "v"(a) : "memory");
  return v;
}
__device__ __forceinline__ void st_wg_u32(u32* p, u32 v) {
  __hip_atomic_store(p, v, __ATOMIC_RELAXED, __HIP_MEMORY_SCOPE_WORKGROUP);
}
__device__ __forceinline__ void st_wg_u16(u16* p, u16 v) {
  __hip_atomic_store(p, v, __ATOMIC_RELAXED, __HIP_MEMORY_SCOPE_WORKGROUP);
}
__device__ __forceinline__ u32 ld_ag(const u32* p) {
  return __hip_atomic_load(p, __ATOMIC_RELAXED, __HIP_MEMORY_SCOPE_AGENT);
}
__device__ __forceinline__ void st_ag_u32(u32* p, u32 v) {
  __hip_atomic_store(p, v, __ATOMIC_RELAXED, __HIP_MEMORY_SCOPE_AGENT);
}

// ---------------- prologue kernels ----------------

__global__ void k_prep(const float* __restrict__ H0, u16* __restrict__ Hbuf0,
                       u32* __restrict__ flags) {
  int i = blockIdx.x * 256 + threadIdx.x;
  if (i < 4096) flags[i] = 0u;            // step flags + xmap + tok + dec + ver
  Hbuf0[i] = f2bf(H0[i]);                 // i < 65536 == BATCH*HU
}

__global__ void k_xconv(const float* __restrict__ in, u16* __restrict__ out) {
  int i = blockIdx.x * 256 + threadIdx.x;
  float4 v = ((const float4*)in)[i];
  ushort4 o;
  o.x = f2bf(v.x); o.y = f2bf(v.y); o.z = f2bf(v.z); o.w = f2bf(v.w);
  ((ushort4*)out)[i] = o;
}

// Wpack[bj(32)][nt(8)][kc(40)][lane(64)][8] bf16 : MFMA B-fragment order.
__global__ void k_pack(const float* __restrict__ Wxi, const float* __restrict__ Whi,
                       const float* __restrict__ Wxf, const float* __restrict__ Whf,
                       const float* __restrict__ Wxo, const float* __restrict__ Who,
                       const float* __restrict__ Wxc, const float* __restrict__ Whc,
                       u16* __restrict__ Wpack) {
  int tid  = blockIdx.x * 256 + threadIdx.x;   // < 32*8*40*64 = 655360
  int lane = tid & 63;
  int kc   = (tid >> 6) % 40;
  int nt   = ((tid >> 6) / 40) & 7;
  int bj   = (tid >> 6) / 320;
  int c    = nt * 16 + (lane & 15);
  int gate = (c >> 3) & 3;
  int h    = bj * 32 + (c >> 5) * 8 + (c & 7);
  const float* Wx = (gate == 0) ? Wxi : (gate == 1) ? Wxf : (gate == 2) ? Wxo : Wxc;
  const float* Wh = (gate == 0) ? Whi : (gate == 1) ? Whf : (gate == 2) ? Who : Whc;
  int kbase = kc * 32 + ((lane >> 4) << 3);
  u16 tmp[8];
#pragma unroll
  for (int e = 0; e < 8; e++) {
    int k = kbase + e;
    float v = (k < DIM) ? Wx[k * HU + h] : Wh[(k - DIM) * HU + h];
    tmp[e] = f2bf(v);
  }
  *(uint4*)(Wpack + (size_t)tid * 8) = *(uint4*)tmp;
}

// pred[b,t] = bd + sum_{g<128} part[t*8192 + g*64 + b];  32768 threads
__global__ void k_predsum(const float* __restrict__ part, const float* __restrict__ bd,
                          float* __restrict__ pred) {
  int i = blockIdx.x * 256 + threadIdx.x;
  int b = i & 63, t = i >> 6;
  float s = bd[0];
  const float* p0 = part + (size_t)t * NB * 64 + b;
#pragma unroll 8
  for (int jj = 0; jj < NB; jj++) s += p0[jj * 64];
  pred[b * SEQ + t] = s;
}

// ---------------- main persistent kernel ----------------

struct MainParams {
  const u16* __restrict__ xbf;     // (B,S,D) bf16
  const u16* __restrict__ Wpack;   // [32][8][40][64][8] bf16
  u16* __restrict__ Hbuf;          // [2][B][HU] bf16 (double buffer)
  const float* __restrict__ C0;
  const float* __restrict__ Wd;
  const float* __restrict__ bi;
  const float* __restrict__ bfg;
  const float* __restrict__ bo;
  const float* __restrict__ bc;
  float* __restrict__ ppart;       // [SEQ][32bj][4wv][64b] pred partials
  float* __restrict__ Hf;          // [B][HU]
  float* __restrict__ Cf;          // [B][HU]
  u32* __restrict__ flags;         // layout per F_* defines
};

__global__ __launch_bounds__(256, 1) void lstm_main(MainParams p) {
  __shared__ __align__(16) u16 Hsm[16 * ROWU];   // 33024 B
  __shared__ int s_roles[4];                     // [2]=rank, [3]=decision

  const int tid  = threadIdx.x;
  const int wv   = tid >> 6, lane = tid & 63;
  const int bid  = blockIdx.x;

  u32* xmap = p.flags + F_XMAP;
  u32* tok  = p.flags + F_TOK;
  u32* d1   = p.flags + F_DEC1;
  u32* d2   = p.flags + F_DEC2;
  u32* ver  = p.flags + F_VER;

  const u32 myxcc = ((u32)__builtin_amdgcn_s_getreg(HWREG_XCC_ID_IMM)) & 7u;

  // ---- consensus phase A: publish placement, vote FAST-try/SLOW ----
  if (tid == 0) st_ag_u32(xmap + bid, 0x100u | myxcc);

  u32* smap = (u32*)Hsm;   // reuse LDS as the 256-entry map scratch
  {
    u32 v = 0; int spins = 0;
    for (;;) {
      v = ld_ag(xmap + tid);
      if (v & 0x100u) break;
      if (ld_ag(d1) != 0u) break;
      if (++spins > 20000) break;               // bounded: residency failure only
      __builtin_amdgcn_s_sleep(2);
    }
    smap[tid] = v;
  }
  __syncthreads();
  if (tid == 0) {
    int cnt[8] = {0, 0, 0, 0, 0, 0, 0, 0};
    bool all = true;
    for (int i = 0; i < 256; i++) {
      u32 v = smap[i];
      if (!(v & 0x100u)) { all = false; break; }
      cnt[v & 7u]++;
    }
    bool ok = all;
    if (ok)
      for (int x = 0; x < 8; x++) ok = ok && (cnt[x] == 32);
    u32 want = ok ? 2u : 1u, exp = 0u, dec = want;
    if (!__hip_atomic_compare_exchange_strong(d1, &exp, want,
          __ATOMIC_RELAXED, __ATOMIC_RELAXED, __HIP_MEMORY_SCOPE_AGENT))
      dec = exp;
    s_roles[3] = (int)dec;
    s_roles[2] = 0;
  }
  __syncthreads();
  int dec = s_roles[3];
  int myrank = 0;

  // ---- consensus phase B: bounded coherence handshake (FAST-try only) ----
  if (dec == 2) {
    {  // refill any map entry this thread missed (published => terminates fast)
      u32 v = smap[tid];
      if (!(v & 0x100u)) {
        int spins = 0;
        do {
          v = ld_ag(xmap + tid);
          if (++spins > 100000) break;
        } while (!(v & 0x100u));
        smap[tid] = v;
      }
    }
    __syncthreads();
    if (tid == 0) {
      bool okh = true;
      for (int i = 0; i < 256; i++) okh = okh && ((smap[i] & 0x100u) != 0u);
      int rank = 0;
      if (okh) {
        for (int i = 0; i < bid; i++) rank += ((smap[i] & 7u) == myxcc) ? 1 : 0;
        // publish token with a PLAIN store (XCD-L2 only), poll group via sc0
        st_wg_u32(tok + myxcc * 32 + rank, 1u);
        int spins = 0;
        for (;;) {
          bool allt = true;
          for (int j = 0; j < 32; j++)
            allt = allt && (l2_load(tok + myxcc * 32 + j) != 0u);
          if (allt) break;
          if (ld_ag(d2) != 0u) { okh = false; break; }   // someone failed
          if (++spins > 20000) { okh = false; break; }
          __builtin_amdgcn_s_sleep(1);
        }
      }
      u32 got;
      if (okh) {
        __hip_atomic_fetch_add(ver, 1u, __ATOMIC_RELAXED, __HIP_MEMORY_SCOPE_AGENT);
        int spins = 0;
        for (;;) {
          u32 dv = ld_ag(d2);
          if (dv != 0u) { got = dv; break; }
          if (ld_ag(ver) >= 256u) {             // all blocks proved visibility
            u32 exp = 0u; got = 2u;
            if (!__hip_atomic_compare_exchange_strong(d2, &exp, 2u,
                  __ATOMIC_RELAXED, __ATOMIC_RELAXED, __HIP_MEMORY_SCOPE_AGENT))
              got = exp;
            break;
          }
          if (++spins > 100000) {
            u32 exp = 0u; got = 1u;
            if (!__hip_atomic_compare_exchange_strong(d2, &exp, 1u,
                  __ATOMIC_RELAXED, __ATOMIC_RELAXED, __HIP_MEMORY_SCOPE_AGENT))
              got = exp;
            break;
          }
          __builtin_amdgcn_s_sleep(1);
        }
      } else {
        u32 exp = 0u; got = 1u;
        if (!__hip_atomic_compare_exchange_strong(d2, &exp, 1u,
              __ATOMIC_RELAXED, __ATOMIC_RELAXED, __HIP_MEMORY_SCOPE_AGENT))
          got = exp;
      }
      // note: dec2==2 implies ver hit 256 => every block had okh && valid rank
      s_roles[3] = (int)got;
      s_roles[2] = rank;
    }
    __syncthreads();
    dec    = s_roles[3];
    myrank = s_roles[2];
  }

  const bool fast = (dec == 2);
  int workf, bb, bj;
  if (fast) { workf = (myxcc < 4u) ? 1 : 0; bb = (int)myxcc; bj = myrank; }
  else      { workf = (bid < NB) ? 1 : 0;   bb = bid & 3;    bj = bid >> 2; }
  if (!workf) return;
  __syncthreads();   // re-align workers after consensus

  const int q    = lane >> 4;              // row quad
  const int q8   = q * 8;                  // k sub-offset in frag
  const int m16  = lane & 15;
  const int hl   = lane & 7;
  const bool hiH = (lane & 8) != 0;        // f/c-holder half

  const int hglob = bj * 32 + wv * 8 + hl; // this thread's h column
  const int row0  = 16 * bb;               // block's first batch row

  // resident weight B-fragments: wave wv owns n-tiles {2wv, 2wv+1}, full K.
  short8 wx[8][2], wh[32][2];
  {
    const u16* wbase = p.Wpack + ((size_t)bj * 8 + 2 * wv) * (40 * 512) + lane * 8;
#pragma unroll
    for (int kc = 0; kc < 8; kc++)
#pragma unroll
      for (int ntl = 0; ntl < 2; ntl++)
        wx[kc][ntl] = *(const short8*)(wbase + ((size_t)ntl * 40 + kc) * 512);
#pragma unroll
    for (int kc = 0; kc < 32; kc++)
#pragma unroll
      for (int ntl = 0; ntl < 2; ntl++)
        wh[kc][ntl] = *(const short8*)(wbase + ((size_t)ntl * 40 + 8 + kc) * 512);
  }

  // per-thread epilogue state: 4 rows (q*4+r), one h
  const float bI = p.bi[hglob],  bF = p.bfg[hglob];
  const float bO = p.bo[hglob],  bC = p.bc[hglob];
  const float wdv = p.Wd[hglob];
  float Cst[4], Hst[4];
#pragma unroll
  for (int r = 0; r < 4; r++) {
    Cst[r] = p.C0[(row0 + q * 4 + r) * HU + hglob];
    Hst[r] = 0.f;
  }

  // LDS read base for A-frags (m = lane&15 -> local row)
  const u16* Aw = Hsm + m16 * ROWU + q8;

  // x fragments for t=0
  uint4 ax[8];
#pragma unroll
  for (int kc = 0; kc < 8; kc++)
    ax[kc] = *(const uint4*)(p.xbf + ((size_t)((row0 + m16) * SEQ + 0)) * DIM
                             + kc * 32 + q8);

#pragma unroll 1
  for (int t = 0; t < SEQ; t++) {
    const int rb = t & 1;
    const u16* Hr = p.Hbuf + (size_t)rb * (BATCH * HU);
    u16*       Hw = p.Hbuf + (size_t)(rb ^ 1) * (BATCH * HU);

    // ---- issue H staging: wave wv -> segments [8wv, 8wv+8) of 32 ----
    if (fast) {
#pragma unroll
      for (int i = 0; i < 8; i++) {
        int s = wv * 8 + i, row = s >> 1, half = s & 1;
        const u16* g = Hr + (size_t)(row0 + row) * HU + half * 512 + lane * 8;
        __builtin_amdgcn_global_load_lds((gptr_t)(const void*)g,
            (lptr_t)(void*)(Hsm + row * ROWU + half * 512), 16, 0, 1);   // sc0: XCD L2
      }
    } else {
#pragma unroll
      for (int i = 0; i < 8; i++) {
        int s = wv * 8 + i, row = s >> 1, half = s & 1;
        const u16* g = Hr + (size_t)(row0 + row) * HU + half * 512 + lane * 8;
        __builtin_amdgcn_global_load_lds((gptr_t)(const void*)g,
            (lptr_t)(void*)(Hsm + row * ROWU + half * 512), 16, 0, 17);  // sc0|sc1: LLC
      }
    }

    // ---- x-phase MFMAs (in the shadow of DMA latency) ----
    f32x4 acc[2][4];
#pragma unroll
    for (int ntl = 0; ntl < 2; ntl++)
#pragma unroll
      for (int c = 0; c < 4; c++) acc[ntl][c] = (f32x4){0.f, 0.f, 0.f, 0.f};
#pragma unroll
    for (int kc = 0; kc < 8; kc++) {
      short8 af = cv8(ax[kc]);
      acc[0][kc & 3] = __builtin_amdgcn_mfma_f32_16x16x32_bf16(af, wx[kc][0], acc[0][kc & 3], 0, 0, 0);
      acc[1][kc & 3] = __builtin_amdgcn_mfma_f32_16x16x32_bf16(af, wx[kc][1], acc[1][kc & 3], 0, 0, 0);
    }

    __syncthreads();   // #1: drains DMA (vmcnt0) + barrier: Hsm complete

    // ---- H-phase MFMAs from LDS (full K per wave, 2 n-tiles) ----
#pragma unroll
    for (int kc = 0; kc < 32; kc++) {
      short8 af = *(const short8*)(Aw + kc * 32);
      acc[0][kc & 3] = __builtin_amdgcn_mfma_f32_16x16x32_bf16(af, wh[kc][0], acc[0][kc & 3], 0, 0, 0);
      acc[1][kc & 3] = __builtin_amdgcn_mfma_f32_16x16x32_bf16(af, wh[kc][1], acc[1][kc & 3], 0, 0, 0);
    }

    // ---- gate combine: ntl=0 -> {i,f}, ntl=1 -> {o,c}; swap via shfl_xor(8) ----
    f32x4 g01 = (acc[0][0] + acc[0][1]) + (acc[0][2] + acc[0][3]);
    f32x4 g23 = (acc[1][0] + acc[1][1]) + (acc[1][2] + acc[1][3]);

    float pr[4];
#pragma unroll
    for (int r = 0; r < 4; r++) {
      float u0 = g01[r], u1 = g23[r];
      float v0 = __shfl_xor(u0, 8);
      float v1 = __shfl_xor(u1, 8);
      float gi = hiH ? v0 : u0, gf = hiH ? u0 : v0;
      float go = hiH ? v1 : u1, gc = hiH ? u1 : v1;
      float iv = sigf(gi + bI), fv = sigf(gf + bF);
      float ov = sigf(go + bO), ct = tanhfast(gc + bC);
      Cst[r] = fv * Cst[r] + iv * ct;
      Hst[r] = ov * tanhfast(Cst[r]);
      pr[r]  = Hst[r] * wdv;
    }

    // publish H_t (bit3==0 lanes; 2B stores, rows q*4+r)
    if (!hiH) {
      if (fast) {
#pragma unroll
        for (int r = 0; r < 4; r++)
          st_wg_u16(Hw + (size_t)(row0 + q * 4 + r) * HU + hglob, f2bf(Hst[r]));
      } else {
#pragma unroll
        for (int r = 0; r < 4; r++)
          __hip_atomic_store(Hw + (size_t)(row0 + q * 4 + r) * HU + hglob,
                             f2bf(Hst[r]), __ATOMIC_RELAXED, __HIP_MEMORY_SCOPE_AGENT);
      }
    }

    // pred partials: reduce over 8 h (both halves redundantly), store 4 rows
#pragma unroll
    for (int r = 0; r < 4; r++) {
      pr[r] += __shfl_xor(pr[r], 1);
      pr[r] += __shfl_xor(pr[r], 2);
      pr[r] += __shfl_xor(pr[r], 4);
    }
    if (m16 == 0) {
      float4 st = {pr[0], pr[1], pr[2], pr[3]};
      *(float4*)(p.ppart + (((size_t)t * 32 + bj) * 4 + wv) * 64 + row0 + q * 4) = st;
    }

    __syncthreads();   // #2: all waves' H/pred stores drained + Hsm reads done

    // ---- x prefetch for t+1: off the drain path; overlaps flag+poll+DMA ----
    {
      const int tn = (t + 1 < SEQ) ? t + 1 : t;
#pragma unroll
      for (int kc = 0; kc < 8; kc++)
        ax[kc] = *(const uint4*)(p.xbf + ((size_t)((row0 + m16) * SEQ + tn)) * DIM
                                 + kc * 32 + q8);
    }

    // ---- flag publish + per-wave poll (no 3rd barrier) ----
    const u32 tf = (u32)(t + 1);
    if (tid == 0) {
      if (fast) st_wg_u32(p.flags + F_STEP + bb * 32 + bj, tf);   // XCD L2
      else      st_ag_u32(p.flags + F_STEP + bb * 32 + bj, tf);   // LLC
    }
    if (lane < 32) {
      const u32* fp = p.flags + F_STEP + bb * 32 + lane;
      if (fast) {
        while (l2_load(fp) < tf) __builtin_amdgcn_s_sleep(1);
      } else {
        while (ld_ag(fp) < tf) __builtin_amdgcn_s_sleep(1);
      }
    }
  }

  // finals
  if (!hiH) {
#pragma unroll
    for (int r = 0; r < 4; r++) {
      int row = row0 + q * 4 + r;
      p.Hf[row * HU + hglob] = Hst[r];
      p.Cf[row * HU + hglob] = Cst[r];
    }
  }
}

// ---------------- launch ----------------

extern "C" void kernel_launch(void* const* d_in, const int* in_sizes, int n_in,
                              void* d_out, int out_size, void* d_ws, size_t ws_size,
                              hipStream_t stream) {
  const float* inputs = (const float*)d_in[0];
  const float* H0  = (const float*)d_in[1];
  const float* C0  = (const float*)d_in[2];
  const float* Wxi = (const float*)d_in[3];
  const float* Whi = (const float*)d_in[4];
  const float* bi  = (const float*)d_in[5];
  const float* Wxf = (const float*)d_in[6];
  const float* Whf = (const float*)d_in[7];
  const float* bf_ = (const float*)d_in[8];
  const float* Wxo = (const float*)d_in[9];
  const float* Who = (const float*)d_in[10];
  const float* bo  = (const float*)d_in[11];
  const float* Wxc = (const float*)d_in[12];
  const float* Whc = (const float*)d_in[13];
  const float* bc  = (const float*)d_in[14];
  const float* Wd  = (const float*)d_in[15];
  const float* bd  = (const float*)d_in[16];

  char* ws = (char*)d_ws;
  u32*   flags = (u32*)ws;                                       // 16384 B
  u16*   Wpack = (u16*)(ws + 16384);                             // 10485760 B
  u16*   xbf   = (u16*)(ws + 16384 + 10485760);                  // 16777216 B
  u16*   Hbuf  = (u16*)(ws + 16384 + 10485760 + 16777216);       // 262144 B
  float* ppart = (float*)(ws + 16384 + 10485760 + 16777216 + 262144); // 16777216 B

  float* pred = (float*)d_out;
  float* Hf   = pred + BATCH * SEQ;
  float* Cf   = Hf + BATCH * HU;

  k_prep<<<256, 256, 0, stream>>>(H0, Hbuf, flags);
  k_xconv<<<8192, 256, 0, stream>>>(inputs, xbf);
  k_pack<<<2560, 256, 0, stream>>>(Wxi, Whi, Wxf, Whf, Wxo, Who, Wxc, Whc, Wpack);

  MainParams prm{xbf, Wpack, Hbuf, C0, Wd, bi, bf_, bo, bc, ppart, Hf, Cf, flags};
  lstm_main<<<dim3(GRID), dim3(256), 0, stream>>>(prm);

  k_predsum<<<128, 256, 0, stream>>>(ppart, bd, pred);
}

// Round 3
// 2702.531 us; speedup vs baseline: 2.9595x; 2.9595x over previous
//
#include <hip/hip_runtime.h>

// LSTM forward, persistent-kernel, R9:
//   R8 post-mortem (7998us, WRITE_SIZE 150MB): SLOW path ran -- and slower
//   than R6 because (a) consensus escape required a completed 256-entry poll
//   -> ~6ms timeout burn, (b) 4B-stride flags put 32 sc1 producers on one
//   LLC line with 4x pollers -> hot-line serialization each step.
//   R9: step loop reverted to EXACT R6 (2.34ms proven: 64B-stride flags,
//   wave0-only poll, 3 barriers, prefetch after barrier #1). Fast path
//   reattempted with a cheap, strictly bounded consensus:
//     A: every block tid0 publishes XCC_ID (agent) + release-add counter.
//        Block0 polls counter==256 (small timeout), checks 32/XCD balance,
//        CAS d1 in {SLOW, FAST-try}. Every tid0 polls d1 with a bounded
//        backstop that CASes SLOW itself -> no global completion needed.
//     B (FAST-try): per-block rank; plain-store token; sc0-poll own XCD's
//        32 tokens (bounded); release-add ver; block0 polls ver==256 ->
//        CAS d2=FAST else SLOW. Any timeout anywhere -> CAS SLOW. All
//        decisions CAS-consistent; all loops bounded.
//   FAST (proven placement + proven intra-L2 visibility): bb = XCC_ID (<4),
//   bj = rank; H publish + flags = plain stores (stay in XCD L2); polls =
//   sc0 loads (bypass L1, hit XCD L2); H staging DMA aux=1 (sc0).
//   SLOW: R6 byte-exact (aux=17, agent/sc1 ops, bid<128 mapping).

#define NB    128
#define GRID  256
#define SEQ   512
#define BATCH 64
#define DIM   256
#define HU    1024
#define ROWU  1032   // u16 row stride: 2064 B -> b128 reads 2-way bank (free)

// flags layout (u32 indices; k_prep zeroes [0,4096))
#define F_STEP 0      // [0,2048)   step flags: (bb*32+bj)*16  (64B stride)
#define F_XMAP 2048   // [2048,2304) xcc map per block
#define F_TOK  2304   // [2304,2560) handshake tokens: xcc*32+rank
#define F_CNT  2560   // publish counter
#define F_DEC1 2561   // placement decision: 0=unset 1=SLOW 2=FAST-try
#define F_DEC2 2562   // final decision:     0=unset 1=SLOW 2=FAST
#define F_VER  2563   // handshake verified-block counter

#define HWREG_XCC_ID_IMM ((31 << 11) | 20)   // hwreg(HW_REG_XCC_ID,0,32)

typedef unsigned short u16;
typedef unsigned int   u32;
typedef unsigned long long u64;
typedef __attribute__((ext_vector_type(8))) short  short8;
typedef __attribute__((ext_vector_type(4))) float  f32x4;

typedef const __attribute__((address_space(1))) void* gptr_t;
typedef __attribute__((address_space(3))) void*       lptr_t;

__device__ __forceinline__ u16 f2bf(float x) {
  u32 u = __float_as_uint(x);
  u32 r = (u + 0x7FFFu + ((u >> 16) & 1u)) >> 16;   // RNE
  return (u16)r;
}
__device__ __forceinline__ float sigf(float x)  { return 1.0f / (1.0f + __expf(-x)); }
__device__ __forceinline__ float tanhfast(float x) { return 1.0f - 2.0f / (1.0f + __expf(2.0f * x)); }
__device__ __forceinline__ short8 cv8(uint4 v) {
  union { uint4 d; short8 s; } u; u.d = v; return u.s;
}
// sc0-only load: bypass L1, read the XCD L2 (sc1 would go to LLC and miss
// data sitting dirty in the local L2).
__device__ __forceinline__ u32 l2_load(const u32* p) {
  u64 a = (u64)p; u32 v;
  asm volatile("global_load_dword %0, %1, off sc0\n\ts_waitcnt vmcnt(0)"
               : "=v"(v) : "v"(a) : "memory");
  return v;
}
__device__ __forceinline__ void st_wg_u32(u32* p, u32 v) {
  __hip_atomic_store(p, v, __ATOMIC_RELAXED, __HIP_MEMORY_SCOPE_WORKGROUP);
}
__device__ __forceinline__ void st_wg_u16(u16* p, u16 v) {
  __hip_atomic_store(p, v, __ATOMIC_RELAXED, __HIP_MEMORY_SCOPE_WORKGROUP);
}
__device__ __forceinline__ u32 ld_ag(const u32* p) {
  return __hip_atomic_load(p, __ATOMIC_RELAXED, __HIP_MEMORY_SCOPE_AGENT);
}
__device__ __forceinline__ void st_ag_u32(u32* p, u32 v) {
  __hip_atomic_store(p, v, __ATOMIC_RELAXED, __HIP_MEMORY_SCOPE_AGENT);
}
__device__ __forceinline__ u32 cas_dec(u32* p, u32 want) {
  u32 exp = 0u;
  if (__hip_atomic_compare_exchange_strong(p, &exp, want,
        __ATOMIC_RELEASE, __ATOMIC_ACQUIRE, __HIP_MEMORY_SCOPE_AGENT))
    return want;
  return exp;   // someone else decided first -- adopt their value
}

// ---------------- prologue kernels ----------------

__global__ void k_prep(const float* __restrict__ H0, u16* __restrict__ Hbuf0,
                       u32* __restrict__ flags) {
  int i = blockIdx.x * 256 + threadIdx.x;
  if (i < 4096) flags[i] = 0u;            // step flags + map + tok + ctrl
  Hbuf0[i] = f2bf(H0[i]);                 // i < 65536 == BATCH*HU
}

__global__ void k_xconv(const float* __restrict__ in, u16* __restrict__ out) {
  int i = blockIdx.x * 256 + threadIdx.x;
  float4 v = ((const float4*)in)[i];
  ushort4 o;
  o.x = f2bf(v.x); o.y = f2bf(v.y); o.z = f2bf(v.z); o.w = f2bf(v.w);
  ((ushort4*)out)[i] = o;
}

// Wpack[bj(32)][nt(8)][kc(40)][lane(64)][8] bf16 : MFMA B-fragment order.
__global__ void k_pack(const float* __restrict__ Wxi, const float* __restrict__ Whi,
                       const float* __restrict__ Wxf, const float* __restrict__ Whf,
                       const float* __restrict__ Wxo, const float* __restrict__ Who,
                       const float* __restrict__ Wxc, const float* __restrict__ Whc,
                       u16* __restrict__ Wpack) {
  int tid  = blockIdx.x * 256 + threadIdx.x;   // < 32*8*40*64 = 655360
  int lane = tid & 63;
  int kc   = (tid >> 6) % 40;
  int nt   = ((tid >> 6) / 40) & 7;
  int bj   = (tid >> 6) / 320;
  int c    = nt * 16 + (lane & 15);
  int gate = (c >> 3) & 3;
  int h    = bj * 32 + (c >> 5) * 8 + (c & 7);
  const float* Wx = (gate == 0) ? Wxi : (gate == 1) ? Wxf : (gate == 2) ? Wxo : Wxc;
  const float* Wh = (gate == 0) ? Whi : (gate == 1) ? Whf : (gate == 2) ? Who : Whc;
  int kbase = kc * 32 + ((lane >> 4) << 3);
  u16 tmp[8];
#pragma unroll
  for (int e = 0; e < 8; e++) {
    int k = kbase + e;
    float v = (k < DIM) ? Wx[k * HU + h] : Wh[(k - DIM) * HU + h];
    tmp[e] = f2bf(v);
  }
  *(uint4*)(Wpack + (size_t)tid * 8) = *(uint4*)tmp;
}

// pred[b,t] = bd + sum_{g<128} part[t*8192 + g*64 + b];  32768 threads
__global__ void k_predsum(const float* __restrict__ part, const float* __restrict__ bd,
                          float* __restrict__ pred) {
  int i = blockIdx.x * 256 + threadIdx.x;
  int b = i & 63, t = i >> 6;
  float s = bd[0];
  const float* p0 = part + (size_t)t * NB * 64 + b;
#pragma unroll 8
  for (int jj = 0; jj < NB; jj++) s += p0[jj * 64];
  pred[b * SEQ + t] = s;
}

// ---------------- main persistent kernel ----------------

struct MainParams {
  const u16* __restrict__ xbf;     // (B,S,D) bf16
  const u16* __restrict__ Wpack;   // [32][8][40][64][8] bf16
  u16* __restrict__ Hbuf;          // [2][B][HU] bf16 (double buffer)
  const float* __restrict__ C0;
  const float* __restrict__ Wd;
  const float* __restrict__ bi;
  const float* __restrict__ bfg;
  const float* __restrict__ bo;
  const float* __restrict__ bc;
  float* __restrict__ ppart;       // [SEQ][32bj][4wv][64b] pred partials
  float* __restrict__ Hf;          // [B][HU]
  float* __restrict__ Cf;          // [B][HU]
  u32* __restrict__ flags;         // layout per F_* defines
};

__global__ __launch_bounds__(256, 1) void lstm_main(MainParams p) {
  __shared__ __align__(16) u16 Hsm[16 * ROWU];   // 33024 B
  __shared__ int s_rank, s_dec;

  const int tid  = threadIdx.x;
  const int wv   = tid >> 6, lane = tid & 63;
  const int bid  = blockIdx.x;

  u32* xmap = p.flags + F_XMAP;
  u32* tok  = p.flags + F_TOK;
  u32* cnt  = p.flags + F_CNT;
  u32* d1   = p.flags + F_DEC1;
  u32* d2   = p.flags + F_DEC2;
  u32* ver  = p.flags + F_VER;

  const u32 myxcc = ((u32)__builtin_amdgcn_s_getreg(HWREG_XCC_ID_IMM)) & 7u;

  // ---- one-time bounded consensus (tid0 only; others wait at barrier) ----
  if (tid == 0) {
    // phase A: publish placement
    st_ag_u32(xmap + bid, 0x100u | myxcc);
    __hip_atomic_fetch_add(cnt, 1u, __ATOMIC_RELEASE, __HIP_MEMORY_SCOPE_AGENT);

    u32 dec1;
    if (bid == 0) {
      bool ok = false; int sp = 0;
      while (sp++ < 2500) {   // ~0.8ms max; typical <10us
        if (__hip_atomic_load(cnt, __ATOMIC_ACQUIRE, __HIP_MEMORY_SCOPE_AGENT) >= (u32)GRID)
          { ok = true; break; }
        __builtin_amdgcn_s_sleep(1);
      }
      if (ok) {
        int c8[8] = {0,0,0,0,0,0,0,0};
        for (int i = 0; i < GRID; i++) {
          u32 v = ld_ag(xmap + i);
          if (!(v & 0x100u)) { ok = false; break; }
          c8[v & 7u]++;
        }
        if (ok)
          for (int x = 0; x < 8; x++) ok = ok && (c8[x] == 32);
      }
      dec1 = cas_dec(d1, ok ? 2u : 1u);
    } else {
      int sp = 0;
      for (;;) {
        dec1 = __hip_atomic_load(d1, __ATOMIC_ACQUIRE, __HIP_MEMORY_SCOPE_AGENT);
        if (dec1 != 0u) break;
        if (sp++ > 6000) { dec1 = cas_dec(d1, 1u); break; }   // backstop -> SLOW
        __builtin_amdgcn_s_sleep(1);
      }
    }

    int rank = 0;
    u32 dec2 = 1u;
    if (dec1 == 2u) {
      // phase B: rank within XCD + intra-L2 visibility handshake
      for (int i = 0; i < bid; i++)
        rank += ((ld_ag(xmap + i) & 7u) == myxcc) ? 1 : 0;
      st_wg_u32(tok + (int)myxcc * 32 + rank, 1u);   // plain store: XCD L2
      bool okh = false; int sp = 0;
      for (;;) {
        bool all = true;
        for (int j = 0; j < 32; j++)
          all = all && (l2_load(tok + (int)myxcc * 32 + j) != 0u);
        if (all) { okh = true; break; }
        if (ld_ag(d2) != 0u) break;                  // decided elsewhere
        if (sp++ > 200) break;                       // ~0.6ms max (32 loads/iter)
        __builtin_amdgcn_s_sleep(1);
      }
      if (okh)
        __hip_atomic_fetch_add(ver, 1u, __ATOMIC_RELEASE, __HIP_MEMORY_SCOPE_AGENT);
      else
        (void)cas_dec(d2, 1u);

      if (bid == 0) {
        int sp2 = 0;
        for (;;) {
          u32 dv = ld_ag(d2);
          if (dv != 0u) { dec2 = dv; break; }
          if (__hip_atomic_load(ver, __ATOMIC_ACQUIRE, __HIP_MEMORY_SCOPE_AGENT) >= (u32)GRID)
            { dec2 = cas_dec(d2, 2u); break; }
          if (sp2++ > 3000) { dec2 = cas_dec(d2, 1u); break; }
          __builtin_amdgcn_s_sleep(1);
        }
      } else {
        int sp2 = 0;
        for (;;) {
          u32 dv = ld_ag(d2);
          if (dv != 0u) { dec2 = dv; break; }
          if (sp2++ > 6000) { dec2 = cas_dec(d2, 1u); break; }
          __builtin_amdgcn_s_sleep(1);
        }
      }
    }
    s_rank = rank;
    s_dec  = (dec1 == 2u) ? (int)dec2 : 1;
  }
  __syncthreads();
  const bool fast  = (s_dec == 2);
  const int myrank = s_rank;

  int workf, bb, bj;
  if (fast) { workf = (myxcc < 4u) ? 1 : 0; bb = (int)myxcc; bj = myrank; }
  else      { workf = (bid < NB) ? 1 : 0;   bb = bid & 3;    bj = bid >> 2; }
  if (!workf) return;

  const int q    = lane >> 4;              // row quad
  const int q8   = q * 8;                  // k sub-offset in frag
  const int m16  = lane & 15;
  const int hl   = lane & 7;
  const bool hiH = (lane & 8) != 0;        // f/c-holder half

  const int hglob = bj * 32 + wv * 8 + hl; // this thread's h column
  const int row0  = 16 * bb;               // block's first batch row

  // resident weight B-fragments: wave wv owns n-tiles {2wv, 2wv+1}, full K.
  short8 wx[8][2], wh[32][2];
  {
    const u16* wbase = p.Wpack + ((size_t)bj * 8 + 2 * wv) * (40 * 512) + lane * 8;
#pragma unroll
    for (int kc = 0; kc < 8; kc++)
#pragma unroll
      for (int ntl = 0; ntl < 2; ntl++)
        wx[kc][ntl] = *(const short8*)(wbase + ((size_t)ntl * 40 + kc) * 512);
#pragma unroll
    for (int kc = 0; kc < 32; kc++)
#pragma unroll
      for (int ntl = 0; ntl < 2; ntl++)
        wh[kc][ntl] = *(const short8*)(wbase + ((size_t)ntl * 40 + 8 + kc) * 512);
  }

  // per-thread epilogue state: 4 rows (q*4+r), one h
  const float bI = p.bi[hglob],  bF = p.bfg[hglob];
  const float bO = p.bo[hglob],  bC = p.bc[hglob];
  const float wdv = p.Wd[hglob];
  float Cst[4], Hst[4];
#pragma unroll
  for (int r = 0; r < 4; r++) {
    Cst[r] = p.C0[(row0 + q * 4 + r) * HU + hglob];
    Hst[r] = 0.f;
  }

  // LDS read base for A-frags (m = lane&15 -> local row)
  const u16* Aw = Hsm + m16 * ROWU + q8;

  // x fragments for t=0
  uint4 ax[8];
#pragma unroll
  for (int kc = 0; kc < 8; kc++)
    ax[kc] = *(const uint4*)(p.xbf + ((size_t)((row0 + m16) * SEQ + 0)) * DIM
                             + kc * 32 + q8);

#pragma unroll 1
  for (int t = 0; t < SEQ; t++) {
    const int rb = t & 1;
    const u16* Hr = p.Hbuf + (size_t)rb * (BATCH * HU);
    u16*       Hw = p.Hbuf + (size_t)(rb ^ 1) * (BATCH * HU);

    // ---- issue H staging: wave wv -> segments [8wv, 8wv+8) of 32 ----
#pragma unroll
    for (int i = 0; i < 8; i++) {
      int s = wv * 8 + i, row = s >> 1, half = s & 1;
      const u16* g = Hr + (size_t)(row0 + row) * HU + half * 512 + lane * 8;
      if (fast)
        __builtin_amdgcn_global_load_lds((gptr_t)(const void*)g,
            (lptr_t)(void*)(Hsm + row * ROWU + half * 512), 16, 0, 1);   // sc0: XCD L2
      else
        __builtin_amdgcn_global_load_lds((gptr_t)(const void*)g,
            (lptr_t)(void*)(Hsm + row * ROWU + half * 512), 16, 0, 17);  // sc0|sc1: LLC
    }

    // ---- x-phase MFMAs (in the shadow of DMA latency) ----
    f32x4 acc[2][4];
#pragma unroll
    for (int ntl = 0; ntl < 2; ntl++)
#pragma unroll
      for (int c = 0; c < 4; c++) acc[ntl][c] = (f32x4){0.f, 0.f, 0.f, 0.f};
#pragma unroll
    for (int kc = 0; kc < 8; kc++) {
      short8 af = cv8(ax[kc]);
      acc[0][kc & 3] = __builtin_amdgcn_mfma_f32_16x16x32_bf16(af, wx[kc][0], acc[0][kc & 3], 0, 0, 0);
      acc[1][kc & 3] = __builtin_amdgcn_mfma_f32_16x16x32_bf16(af, wx[kc][1], acc[1][kc & 3], 0, 0, 0);
    }

    __syncthreads();   // #1: drains DMA (vmcnt0) + barrier: Hsm complete

    // ---- x prefetch for t+1 (completes during H phase / next flag wait) ----
    {
      const int tn = (t + 1 < SEQ) ? t + 1 : t;
#pragma unroll
      for (int kc = 0; kc < 8; kc++)
        ax[kc] = *(const uint4*)(p.xbf + ((size_t)((row0 + m16) * SEQ + tn)) * DIM
                                 + kc * 32 + q8);
    }

    // ---- H-phase MFMAs from LDS (full K per wave, 2 n-tiles) ----
#pragma unroll
    for (int kc = 0; kc < 32; kc++) {
      short8 af = *(const short8*)(Aw + kc * 32);
      acc[0][kc & 3] = __builtin_amdgcn_mfma_f32_16x16x32_bf16(af, wh[kc][0], acc[0][kc & 3], 0, 0, 0);
      acc[1][kc & 3] = __builtin_amdgcn_mfma_f32_16x16x32_bf16(af, wh[kc][1], acc[1][kc & 3], 0, 0, 0);
    }

    // ---- gate combine: ntl=0 -> {i,f}, ntl=1 -> {o,c}; swap via shfl_xor(8) ----
    f32x4 g01 = (acc[0][0] + acc[0][1]) + (acc[0][2] + acc[0][3]);
    f32x4 g23 = (acc[1][0] + acc[1][1]) + (acc[1][2] + acc[1][3]);

    float pr[4];
#pragma unroll
    for (int r = 0; r < 4; r++) {
      float u0 = g01[r], u1 = g23[r];
      float v0 = __shfl_xor(u0, 8);
      float v1 = __shfl_xor(u1, 8);
      float gi = hiH ? v0 : u0, gf = hiH ? u0 : v0;
      float go = hiH ? v1 : u1, gc = hiH ? u1 : v1;
      float iv = sigf(gi + bI), fv = sigf(gf + bF);
      float ov = sigf(go + bO), ct = tanhfast(gc + bC);
      Cst[r] = fv * Cst[r] + iv * ct;
      Hst[r] = ov * tanhfast(Cst[r]);
      pr[r]  = Hst[r] * wdv;
    }

    // publish H_t (bit3==0 lanes; 2B stores, rows q*4+r)
    if (!hiH) {
      if (fast) {
#pragma unroll
        for (int r = 0; r < 4; r++)
          st_wg_u16(Hw + (size_t)(row0 + q * 4 + r) * HU + hglob, f2bf(Hst[r]));   // XCD L2
      } else {
#pragma unroll
        for (int r = 0; r < 4; r++)
          __hip_atomic_store(Hw + (size_t)(row0 + q * 4 + r) * HU + hglob,
                             f2bf(Hst[r]), __ATOMIC_RELAXED, __HIP_MEMORY_SCOPE_AGENT);
      }
    }

    // pred partials: reduce over 8 h (both halves redundantly), store 4 rows
#pragma unroll
    for (int r = 0; r < 4; r++) {
      pr[r] += __shfl_xor(pr[r], 1);
      pr[r] += __shfl_xor(pr[r], 2);
      pr[r] += __shfl_xor(pr[r], 4);
    }
    if (m16 == 0) {
      float4 st = {pr[0], pr[1], pr[2], pr[3]};
      *(float4*)(p.ppart + (((size_t)t * 32 + bj) * 4 + wv) * 64 + row0 + q * 4) = st;
    }

    // ---- distributed flag barrier: only the 32 same-bb producers ----
    __syncthreads();   // #2: drains vmcnt -> H stores at L2/LLC before flag
    const u32 tf = (u32)(t + 1);
    if (tid == 0) {
      if (fast) st_wg_u32(p.flags + F_STEP + (bb * 32 + bj) * 16, tf);
      else      st_ag_u32(p.flags + F_STEP + (bb * 32 + bj) * 16, tf);
    }
    if (tid < 32) {
      const u32* fp = p.flags + F_STEP + (bb * 32 + tid) * 16;
      if (fast) { while (l2_load(fp) < tf) __builtin_amdgcn_s_sleep(1); }
      else      { while (ld_ag(fp)  < tf) __builtin_amdgcn_s_sleep(1); }
    }
    __syncthreads();   // #3
  }

  // finals
  if (!hiH) {
#pragma unroll
    for (int r = 0; r < 4; r++) {
      int row = row0 + q * 4 + r;
      p.Hf[row * HU + hglob] = Hst[r];
      p.Cf[row * HU + hglob] = Cst[r];
    }
  }
}

// ---------------- launch ----------------

extern "C" void kernel_launch(void* const* d_in, const int* in_sizes, int n_in,
                              void* d_out, int out_size, void* d_ws, size_t ws_size,
                              hipStream_t stream) {
  const float* inputs = (const float*)d_in[0];
  const float* H0  = (const float*)d_in[1];
  const float* C0  = (const float*)d_in[2];
  const float* Wxi = (const float*)d_in[3];
  const float* Whi = (const float*)d_in[4];
  const float* bi  = (const float*)d_in[5];
  const float* Wxf = (const float*)d_in[6];
  const float* Whf = (const float*)d_in[7];
  const float* bf_ = (const float*)d_in[8];
  const float* Wxo = (const float*)d_in[9];
  const float* Who = (const float*)d_in[10];
  const float* bo  = (const float*)d_in[11];
  const float* Wxc = (const float*)d_in[12];
  const float* Whc = (const float*)d_in[13];
  const float* bc  = (const float*)d_in[14];
  const float* Wd  = (const float*)d_in[15];
  const float* bd  = (const float*)d_in[16];

  char* ws = (char*)d_ws;
  u32*   flags = (u32*)ws;                                       // 16384 B
  u16*   Wpack = (u16*)(ws + 16384);                             // 10485760 B
  u16*   xbf   = (u16*)(ws + 16384 + 10485760);                  // 16777216 B
  u16*   Hbuf  = (u16*)(ws + 16384 + 10485760 + 16777216);       // 262144 B
  float* ppart = (float*)(ws + 16384 + 10485760 + 16777216 + 262144); // 16777216 B

  float* pred = (float*)d_out;
  float* Hf   = pred + BATCH * SEQ;
  float* Cf   = Hf + BATCH * HU;

  k_prep<<<256, 256, 0, stream>>>(H0, Hbuf, flags);
  k_xconv<<<8192, 256, 0, stream>>>(inputs, xbf);
  k_pack<<<2560, 256, 0, stream>>>(Wxi, Whi, Wxf, Whf, Wxo, Who, Wxc, Whc, Wpack);

  MainParams prm{xbf, Wpack, Hbuf, C0, Wd, bi, bf_, bo, bc, ppart, Hf, Cf, flags};
  lstm_main<<<dim3(GRID), dim3(256), 0, stream>>>(prm);

  k_predsum<<<128, 256, 0, stream>>>(ppart, bd, pred);
}

// Round 4
// 2501.457 us; speedup vs baseline: 3.1973x; 1.0804x over previous
//
#include <hip/hip_runtime.h>

// LSTM forward, persistent-kernel, R10:
//   R7-R9 post-mortem: XCD-local fast path never engaged. R9's overhead
//   signature (+200-370us, exactly a phase-B timeout) shows placement WAS
//   balanced but plain-store -> sc0-load intra-XCD visibility failed on this
//   machine. Abandoned; grid back to 128, no consensus.
//   R10 = R6 (proven 2341us) + H-publish write-amplification fix:
//   R6 wrote each 64B Hbuf line via 4 waves x scattered 2B stores ->
//   partial-line RMW at memory (WRITE_SIZE 150MB vs ~85MB clean, FETCH
//   inflated too); the pre-flag vmcnt(0) drain waits on those RMW acks on
//   the inter-block critical chain every step.
//   Fix: epilogue lanes ds_write H into Hstg[16][32] (1KB LDS, 2-way banks
//   = free); after barrier #2 wave0 alone re-reads and publishes Hbuf with
//   8B/lane agent stores -- every 64B line written contiguously by one
//   instruction (2 instrs, 16 clean lines) -> no partial-line packets,
//   single clean ack before flag. Everything else byte-exact R6.

#define NB   128
#define SEQ  512
#define BATCH 64
#define DIM  256
#define HU   1024
#define ROWU 1032   // u16 row stride: 2064 B = 16 mod 128 -> b128 2-way (free)

typedef unsigned short u16;
typedef unsigned int   u32;
typedef unsigned long long u64;
typedef __attribute__((ext_vector_type(8))) short  short8;
typedef __attribute__((ext_vector_type(4))) float  f32x4;

typedef const __attribute__((address_space(1))) void* gptr_t;
typedef __attribute__((address_space(3))) void*       lptr_t;

__device__ __forceinline__ u16 f2bf(float x) {
  u32 u = __float_as_uint(x);
  u32 r = (u + 0x7FFFu + ((u >> 16) & 1u)) >> 16;   // RNE
  return (u16)r;
}
__device__ __forceinline__ float sigf(float x)  { return 1.0f / (1.0f + __expf(-x)); }
__device__ __forceinline__ float tanhfast(float x) { return 1.0f - 2.0f / (1.0f + __expf(2.0f * x)); }
__device__ __forceinline__ short8 cv8(uint4 v) {
  union { uint4 d; short8 s; } u; u.d = v; return u.s;
}

// ---------------- prologue kernels ----------------

__global__ void k_prep(const float* __restrict__ H0, u16* __restrict__ Hbuf0,
                       u32* __restrict__ flags) {
  int i = blockIdx.x * 256 + threadIdx.x;
  if (i < 2048) flags[i] = 0u;
  Hbuf0[i] = f2bf(H0[i]);   // i < 65536 == BATCH*HU
}

__global__ void k_xconv(const float* __restrict__ in, u16* __restrict__ out) {
  int i = blockIdx.x * 256 + threadIdx.x;
  float4 v = ((const float4*)in)[i];
  ushort4 o;
  o.x = f2bf(v.x); o.y = f2bf(v.y); o.z = f2bf(v.z); o.w = f2bf(v.w);
  ((ushort4*)out)[i] = o;
}

// Wpack[bj(32)][nt(8)][kc(40)][lane(64)][8] bf16 : MFMA B-fragment order.
// local col c = nt*16 + (lane&15) in [0,128):
//   h_high=c>>5, gate=(c>>3)&3, h_low=c&7, h = bj*32 + h_high*8 + h_low
__global__ void k_pack(const float* __restrict__ Wxi, const float* __restrict__ Whi,
                       const float* __restrict__ Wxf, const float* __restrict__ Whf,
                       const float* __restrict__ Wxo, const float* __restrict__ Who,
                       const float* __restrict__ Wxc, const float* __restrict__ Whc,
                       u16* __restrict__ Wpack) {
  int tid  = blockIdx.x * 256 + threadIdx.x;   // < 32*8*40*64 = 655360
  int lane = tid & 63;
  int kc   = (tid >> 6) % 40;
  int nt   = ((tid >> 6) / 40) & 7;
  int bj   = (tid >> 6) / 320;
  int c    = nt * 16 + (lane & 15);
  int gate = (c >> 3) & 3;
  int h    = bj * 32 + (c >> 5) * 8 + (c & 7);
  const float* Wx = (gate == 0) ? Wxi : (gate == 1) ? Wxf : (gate == 2) ? Wxo : Wxc;
  const float* Wh = (gate == 0) ? Whi : (gate == 1) ? Whf : (gate == 2) ? Who : Whc;
  int kbase = kc * 32 + ((lane >> 4) << 3);
  u16 tmp[8];
#pragma unroll
  for (int e = 0; e < 8; e++) {
    int k = kbase + e;
    float v = (k < DIM) ? Wx[k * HU + h] : Wh[(k - DIM) * HU + h];
    tmp[e] = f2bf(v);
  }
  *(uint4*)(Wpack + (size_t)tid * 8) = *(uint4*)tmp;
}

// pred[b,t] = bd + sum_{g<128} part[t*8192 + g*64 + b];  32768 threads
__global__ void k_predsum(const float* __restrict__ part, const float* __restrict__ bd,
                          float* __restrict__ pred) {
  int i = blockIdx.x * 256 + threadIdx.x;
  int b = i & 63, t = i >> 6;
  float s = bd[0];
  const float* p0 = part + (size_t)t * NB * 64 + b;
#pragma unroll 8
  for (int jj = 0; jj < NB; jj++) s += p0[jj * 64];
  pred[b * SEQ + t] = s;
}

// ---------------- main persistent kernel ----------------

struct MainParams {
  const u16* __restrict__ xbf;     // (B,S,D) bf16
  const u16* __restrict__ Wpack;   // [32][8][40][64][8] bf16
  u16* __restrict__ Hbuf;          // [2][B][HU] bf16 (double buffer)
  const float* __restrict__ C0;
  const float* __restrict__ Wd;
  const float* __restrict__ bi;
  const float* __restrict__ bfg;
  const float* __restrict__ bo;
  const float* __restrict__ bc;
  float* __restrict__ ppart;       // [SEQ][32bj][4wv][64b] pred partials
  float* __restrict__ Hf;          // [B][HU]
  float* __restrict__ Cf;          // [B][HU]
  u32* __restrict__ flags;         // [4bb][32bj] stride-16 u32
};

__global__ __launch_bounds__(256, 1) void lstm_main(MainParams p) {
  __shared__ __align__(16) u16 Hsm[16 * ROWU];   // 33024 B
  __shared__ __align__(16) u16 Hstg[16 * 32];    // 1KB H-publish staging

  const int tid  = threadIdx.x;
  const int wv   = tid >> 6, lane = tid & 63;
  const int bj   = blockIdx.x >> 2, bb = blockIdx.x & 3;
  const int q    = lane >> 4;              // row quad
  const int q8   = q * 8;                  // k sub-offset in frag
  const int m16  = lane & 15;
  const int hl   = lane & 7;
  const bool hiH = (lane & 8) != 0;        // f/c-holder half

  const int hglob = bj * 32 + wv * 8 + hl; // this thread's h column
  const int row0  = 16 * bb;               // block's first batch row

  // resident weight B-fragments: wave wv owns n-tiles {2wv, 2wv+1}, full K.
  short8 wx[8][2], wh[32][2];
  {
    const u16* wbase = p.Wpack + ((size_t)bj * 8 + 2 * wv) * (40 * 512) + lane * 8;
#pragma unroll
    for (int kc = 0; kc < 8; kc++)
#pragma unroll
      for (int ntl = 0; ntl < 2; ntl++)
        wx[kc][ntl] = *(const short8*)(wbase + ((size_t)ntl * 40 + kc) * 512);
#pragma unroll
    for (int kc = 0; kc < 32; kc++)
#pragma unroll
      for (int ntl = 0; ntl < 2; ntl++)
        wh[kc][ntl] = *(const short8*)(wbase + ((size_t)ntl * 40 + 8 + kc) * 512);
  }

  // per-thread epilogue state: 4 rows (q*4+r), one h
  const float bI = p.bi[hglob],  bF = p.bfg[hglob];
  const float bO = p.bo[hglob],  bC = p.bc[hglob];
  const float wdv = p.Wd[hglob];
  float Cst[4], Hst[4];
#pragma unroll
  for (int r = 0; r < 4; r++) {
    Cst[r] = p.C0[(row0 + q * 4 + r) * HU + hglob];
    Hst[r] = 0.f;
  }

  // LDS read base for A-frags (m = lane&15 -> local row)
  const u16* Aw = Hsm + m16 * ROWU + q8;

  // x fragments for t=0: row = row0 + m16, k = kc*32 + q8
  uint4 ax[8];
#pragma unroll
  for (int kc = 0; kc < 8; kc++)
    ax[kc] = *(const uint4*)(p.xbf + ((size_t)((row0 + m16) * SEQ + 0)) * DIM
                             + kc * 32 + q8);

#pragma unroll 1
  for (int t = 0; t < SEQ; t++) {
    const int rb = t & 1;
    const u16* Hr = p.Hbuf + (size_t)rb * (BATCH * HU);
    u16*       Hw = p.Hbuf + (size_t)(rb ^ 1) * (BATCH * HU);

    // ---- issue H staging: wave wv -> segments [8wv, 8wv+8) of 32 ----
    // segment s: row = s>>1, cols [(s&1)*512, +512); aux=17 (LLC-coherent DMA)
#pragma unroll
    for (int i = 0; i < 8; i++) {
      int s = wv * 8 + i, row = s >> 1, half = s & 1;
      const u16* g = Hr + (size_t)(row0 + row) * HU + half * 512 + lane * 8;
      __builtin_amdgcn_global_load_lds((gptr_t)(const void*)g,
          (lptr_t)(void*)(Hsm + row * ROWU + half * 512), 16, 0, 17);
    }

    // ---- x-phase MFMAs (in the shadow of DMA latency) ----
    f32x4 acc[2][4];
#pragma unroll
    for (int ntl = 0; ntl < 2; ntl++)
#pragma unroll
      for (int c = 0; c < 4; c++) acc[ntl][c] = (f32x4){0.f, 0.f, 0.f, 0.f};
#pragma unroll
    for (int kc = 0; kc < 8; kc++) {
      short8 af = cv8(ax[kc]);
      acc[0][kc & 3] = __builtin_amdgcn_mfma_f32_16x16x32_bf16(af, wx[kc][0], acc[0][kc & 3], 0, 0, 0);
      acc[1][kc & 3] = __builtin_amdgcn_mfma_f32_16x16x32_bf16(af, wx[kc][1], acc[1][kc & 3], 0, 0, 0);
    }

    __syncthreads();   // #1: drains DMA (vmcnt0) + barrier: Hsm complete

    // ---- x prefetch for t+1 (completes during H phase / next flag wait) ----
    {
      const int tn = (t + 1 < SEQ) ? t + 1 : t;
#pragma unroll
      for (int kc = 0; kc < 8; kc++)
        ax[kc] = *(const uint4*)(p.xbf + ((size_t)((row0 + m16) * SEQ + tn)) * DIM
                                 + kc * 32 + q8);
    }

    // ---- H-phase MFMAs from LDS (full K per wave, 2 n-tiles) ----
#pragma unroll
    for (int kc = 0; kc < 32; kc++) {
      short8 af = *(const short8*)(Aw + kc * 32);
      acc[0][kc & 3] = __builtin_amdgcn_mfma_f32_16x16x32_bf16(af, wh[kc][0], acc[0][kc & 3], 0, 0, 0);
      acc[1][kc & 3] = __builtin_amdgcn_mfma_f32_16x16x32_bf16(af, wh[kc][1], acc[1][kc & 3], 0, 0, 0);
    }

    // ---- gate combine: ntl=0 -> {i,f}, ntl=1 -> {o,c}; swap via shfl_xor(8) ----
    f32x4 g01 = (acc[0][0] + acc[0][1]) + (acc[0][2] + acc[0][3]);
    f32x4 g23 = (acc[1][0] + acc[1][1]) + (acc[1][2] + acc[1][3]);

    float pr[4];
#pragma unroll
    for (int r = 0; r < 4; r++) {
      float u0 = g01[r], u1 = g23[r];
      float v0 = __shfl_xor(u0, 8);
      float v1 = __shfl_xor(u1, 8);
      float gi = hiH ? v0 : u0, gf = hiH ? u0 : v0;
      float go = hiH ? v1 : u1, gc = hiH ? u1 : v1;
      float iv = sigf(gi + bI), fv = sigf(gf + bF);
      float ov = sigf(go + bO), ct = tanhfast(gc + bC);
      Cst[r] = fv * Cst[r] + iv * ct;
      Hst[r] = ov * tanhfast(Cst[r]);
      pr[r]  = Hst[r] * wdv;
    }

    // stage H_t into LDS (bit3==0 lanes; rows q*4+r, col wv*8+hl; 2-way banks)
    if (!hiH) {
#pragma unroll
      for (int r = 0; r < 4; r++)
        Hstg[(q * 4 + r) * 32 + wv * 8 + hl] = f2bf(Hst[r]);
    }

    // pred partials: reduce over 8 h (both halves redundantly), store 4 rows
#pragma unroll
    for (int r = 0; r < 4; r++) {
      pr[r] += __shfl_xor(pr[r], 1);
      pr[r] += __shfl_xor(pr[r], 2);
      pr[r] += __shfl_xor(pr[r], 4);
    }
    if (m16 == 0) {
      float4 st = {pr[0], pr[1], pr[2], pr[3]};
      *(float4*)(p.ppart + (((size_t)t * 32 + bj) * 4 + wv) * 64 + row0 + q * 4) = st;
    }

    __syncthreads();   // #2: Hstg complete; ppart/prefetch draining

    // ---- wave0: publish H_t as 16 clean full-line (64B) stores ----
    // 2 instructions x 64 lanes x 8B; lanes 8k..8k+7 cover one line each.
    if (wv == 0) {
#pragma unroll
      for (int g2 = 0; g2 < 2; g2++) {
        int g = g2 * 64 + lane, row = g >> 3, c8 = g & 7;
        u64 v = *(const u64*)&Hstg[row * 32 + c8 * 4];
        __hip_atomic_store((u64*)(Hw + (size_t)(row0 + row) * HU + bj * 32) + c8,
                           v, __ATOMIC_RELAXED, __HIP_MEMORY_SCOPE_AGENT);
      }
      asm volatile("s_waitcnt vmcnt(0)" ::: "memory");   // H at LLC before flag
    }

    // ---- distributed flag barrier: only the 32 same-bb producers ----
    if (tid == 0)
      __hip_atomic_store(p.flags + (bb * 32 + bj) * 16, (u32)(t + 1),
                         __ATOMIC_RELAXED, __HIP_MEMORY_SCOPE_AGENT);
    if (tid < 32) {
      const u32* f = p.flags + (bb * 32 + tid) * 16;
      while (__hip_atomic_load(f, __ATOMIC_RELAXED, __HIP_MEMORY_SCOPE_AGENT) < (u32)(t + 1))
        __builtin_amdgcn_s_sleep(1);
    }
    __syncthreads();   // #3
  }

  // finals
  if (!hiH) {
#pragma unroll
    for (int r = 0; r < 4; r++) {
      int row = row0 + q * 4 + r;
      p.Hf[row * HU + hglob] = Hst[r];
      p.Cf[row * HU + hglob] = Cst[r];
    }
  }
}

// ---------------- launch ----------------

extern "C" void kernel_launch(void* const* d_in, const int* in_sizes, int n_in,
                              void* d_out, int out_size, void* d_ws, size_t ws_size,
                              hipStream_t stream) {
  const float* inputs = (const float*)d_in[0];
  const float* H0  = (const float*)d_in[1];
  const float* C0  = (const float*)d_in[2];
  const float* Wxi = (const float*)d_in[3];
  const float* Whi = (const float*)d_in[4];
  const float* bi  = (const float*)d_in[5];
  const float* Wxf = (const float*)d_in[6];
  const float* Whf = (const float*)d_in[7];
  const float* bf_ = (const float*)d_in[8];
  const float* Wxo = (const float*)d_in[9];
  const float* Who = (const float*)d_in[10];
  const float* bo  = (const float*)d_in[11];
  const float* Wxc = (const float*)d_in[12];
  const float* Whc = (const float*)d_in[13];
  const float* bc  = (const float*)d_in[14];
  const float* Wd  = (const float*)d_in[15];
  const float* bd  = (const float*)d_in[16];

  char* ws = (char*)d_ws;
  u32*   flags = (u32*)ws;                                      // 8192 B
  u16*   Wpack = (u16*)(ws + 8192);                             // 10485760 B
  u16*   xbf   = (u16*)(ws + 8192 + 10485760);                  // 16777216 B
  u16*   Hbuf  = (u16*)(ws + 8192 + 10485760 + 16777216);       // 262144 B
  float* ppart = (float*)(ws + 8192 + 10485760 + 16777216 + 262144); // 16777216 B

  float* pred = (float*)d_out;
  float* Hf   = pred + BATCH * SEQ;
  float* Cf   = Hf + BATCH * HU;

  k_prep<<<256, 256, 0, stream>>>(H0, Hbuf, flags);
  k_xconv<<<8192, 256, 0, stream>>>(inputs, xbf);
  k_pack<<<2560, 256, 0, stream>>>(Wxi, Whi, Wxf, Whf, Wxo, Who, Wxc, Whc, Wpack);

  MainParams prm{xbf, Wpack, Hbuf, C0, Wd, bi, bf_, bo, bc, ppart, Hf, Cf, flags};
  lstm_main<<<dim3(NB), dim3(256), 0, stream>>>(prm);

  k_predsum<<<128, 256, 0, stream>>>(ppart, bd, pred);
}